// Round 8
// baseline (115.909 us; speedup 1.0000x reference)
//
#include <hip/hip_runtime.h>
#include <hip/hip_bf16.h>

// ProjectionAggregating: B=4096, N=64, D=128
// out[b,d] = query_emb + final_refer / (1e-9 + ref_norm/query_norm*2.5)
// final_refer[b,d] = sum_n (h1@W2^T + b2)[b,n,d] * (refer_embs - start_embs*refer_r)[b,n,d]
// h1 = relu(query_r@W1a^T + refer_r@W1b^T + b1)   (W1a = W1[:, :128], W1b = W1[:, 128:])

typedef __attribute__((ext_vector_type(8))) short bf16x8;   // 8 bf16 = 4 VGPRs (MFMA A/B frag)
typedef __attribute__((ext_vector_type(4))) float f32x4;    // MFMA C/D frag

// Workgroup barrier WITHOUT the vmcnt(0) drain __syncthreads() emits.
// lgkmcnt(0) retires ds_writes into LDS before the barrier (full LDS
// producer->consumer ordering); global loads stay in flight across it.
#define WG_BARRIER()                                            \
    do {                                                        \
        asm volatile("s_waitcnt lgkmcnt(0)" ::: "memory");      \
        __builtin_amdgcn_s_barrier();                           \
    } while (0)

__device__ __forceinline__ unsigned short f2bf(float x) {      // RNE
    unsigned int u = __float_as_uint(x);
    u += 0x7FFFu + ((u >> 16) & 1u);
    return (unsigned short)(u >> 16);
}
// pack two f32 -> two bf16 (round-half-up; inputs are finite randn, no inf/nan)
__device__ __forceinline__ unsigned int pack2bf(float lo, float hi) {
    unsigned int ulo = __float_as_uint(lo) + 0x8000u;
    unsigned int uhi = __float_as_uint(hi) + 0x8000u;
    return (ulo >> 16) | (uhi & 0xFFFF0000u);
}

// ---- kernel 1: convert W1b (W1[:,128:256]) and W2 to bf16 into workspace ----
__global__ __launch_bounds__(256) void pa_prep(const float* __restrict__ W1,
                                               const float* __restrict__ W2,
                                               unsigned short* __restrict__ w1b,
                                               unsigned short* __restrict__ w2b) {
    int i = blockIdx.x * 256 + threadIdx.x;   // grid covers 32768
    if (i < 16384) {
        int d = i >> 7, k = i & 127;
        w1b[i] = f2bf(W1[d * 256 + 128 + k]);
    } else {
        int j = i - 16384;
        w2b[j] = f2bf(W2[j]);
    }
}

// ---- kernel 2: qv[b,d] = b1[d] + sum_k query_r[b,k] * W1[d,k]  (f32, exact) ----
__global__ __launch_bounds__(256) void pa_qv(const float* __restrict__ query_r,
                                             const float* __restrict__ W1,
                                             const float* __restrict__ b1,
                                             float* __restrict__ qv) {
    __shared__ float wa[128][129];
    __shared__ float sq[32][128];
    const int tid = threadIdx.x;
    const int b0 = blockIdx.x * 32;  // grid = 128 blocks

    for (int i = tid; i < 128 * 128; i += 256) {
        int d = i >> 7, k = i & 127;
        wa[d][k] = W1[d * 256 + k];
    }
    for (int i = tid; i < 32 * 128; i += 256) {
        sq[i >> 7][i & 127] = query_r[(size_t)b0 * 128 + i];
    }
    __syncthreads();

    const int d = tid & 127;
    const int rb = (tid >> 7) * 16;
    const float bb = b1[d];
    for (int j = 0; j < 16; ++j) {
        int r = rb + j;
        float a0 = 0.f, a1 = 0.f, a2 = 0.f, a3 = 0.f;
        #pragma unroll
        for (int k = 0; k < 128; k += 4) {
            a0 += sq[r][k + 0] * wa[d][k + 0];
            a1 += sq[r][k + 1] * wa[d][k + 1];
            a2 += sq[r][k + 2] * wa[d][k + 2];
            a3 += sq[r][k + 3] * wa[d][k + 3];
        }
        qv[(size_t)(b0 + r) * 128 + d] = bb + ((a0 + a1) + (a2 + a3));
    }
}

// ---- kernel 3: main fused kernel, one block per b ----
// Staging via global_load_lds (zero VGPR, one trip); refer_r kept f32 in LDS
// with a 16B-chunk XOR swizzle applied on the SOURCE address (linear LDS dest,
// rule #21); attn stays in acc2 registers -> per-lane e/s loads at C/D coords,
// shfl reduce. 4 barriers (was 6), no epi2/gather LDS round-trip.
__global__ __launch_bounds__(256, 2) void pa_main(
    const float* __restrict__ query_emb,
    const float* __restrict__ refer_embs,
    const float* __restrict__ refer_r,
    const float* __restrict__ start_embs,
    const float* __restrict__ qv,
    const unsigned short* __restrict__ w1b,
    const unsigned short* __restrict__ w2b,
    const float* __restrict__ b2,
    float* __restrict__ out) {
    __shared__ __align__(16) float sR[64 * 128];           // refer_r f32, chunk-swizzled (32 KB)
    __shared__ __align__(16) unsigned short sH[64 * 128];  // h1 bf16, swizzled (16 KB)
    __shared__ float sFin[128];
    __shared__ float sRed[4];

    const int b    = blockIdx.x;
    const int tid  = threadIdx.x;
    const int lane = tid & 63;
    const int wv   = tid >> 6;       // 4 waves; wave wv owns output cols [32*wv, 32*wv+32)
    const int hl   = lane & 15;
    const int qh   = lane >> 4;
    const int wcol = wv * 32;

    const size_t base = (size_t)b * 8192;

    // ---- prologue: small per-lane loads (all retired at B1) ----
    float qe   = (tid < 128) ? query_emb[(size_t)b * 128 + tid] : 0.f;
    float qv0  = qv[(size_t)b * 128 + wcol + hl];
    float qv1  = qv[(size_t)b * 128 + wcol + 16 + hl];
    float b2v0 = b2[wcol + hl];
    float b2v1 = b2[wcol + 16 + hl];
    bf16x8 bW[2][4], bW2[2][4];
    #pragma unroll
    for (int ct = 0; ct < 2; ++ct)
        #pragma unroll
        for (int ks = 0; ks < 4; ++ks) {
            bW [ct][ks] = *(const bf16x8*)(w1b + (wcol + ct * 16 + hl) * 128 + ks * 32 + qh * 8);
            bW2[ct][ks] = *(const bf16x8*)(w2b + (wcol + ct * 16 + hl) * 128 + ks * 32 + qh * 8);
        }

    // ---- stage refer_r f32 -> LDS via global_load_lds (no VGPRs, 1 trip) ----
    // LDS image[row][c'] = global[row][c' ^ (row&7)]  (c' = 16B chunk, 32/row).
    // gll writes linearly (wave-uniform base + lane*16); permutation applied
    // on the per-lane SOURCE address. Wave wv covers rows wv*16 .. wv*16+15.
    {
        const float* gR = refer_r + base;
        #pragma unroll
        for (int i = 0; i < 8; ++i) {
            int row   = wv * 16 + 2 * i + (lane >> 5);
            int chunk = (lane & 31) ^ (row & 7);
            __builtin_amdgcn_global_load_lds(
                (const __attribute__((address_space(1))) unsigned int*)(gR + row * 128 + chunk * 4),
                (__attribute__((address_space(3))) unsigned int*)(sR + wv * 2048 + i * 256),
                16, 0, 0);
        }
    }
    __syncthreads();   // B1: gll drain (vmcnt) + barrier; prologue loads also retired

    // ---- issue FULL e/s stream at C/D coordinates (consumed after GEMM2; the
    //      only barrier in between is lgkm-only, so these stay in flight) ----
    float fe[32], fs[32];   // [ct*16 + rt*4 + j], statically indexed
    {
        const float* gE = refer_embs + base;
        const float* gS = start_embs + base;
        #pragma unroll
        for (int ct = 0; ct < 2; ++ct)
            #pragma unroll
            for (int rt = 0; rt < 4; ++rt)
                #pragma unroll
                for (int j = 0; j < 4; ++j) {
                    int row = rt * 16 + qh * 4 + j;
                    int col = wcol + ct * 16 + hl;
                    int o   = row * 128 + col;
                    fe[ct * 16 + rt * 4 + j] = gE[o];
                    fs[ct * 16 + rt * 4 + j] = gS[o];
                }
    }

    // ---- GEMM1: h1_part[row,col] = sum_k refer_r[row,k] * W1b[col,k] ----
    // A-frag: read 2 swizzled f32 chunks, pack to bf16x8 inline.
    f32x4 acc1[4][2] = {};
    #pragma unroll
    for (int rt = 0; rt < 4; ++rt) {
        const int row = rt * 16 + hl;
        const int sw  = row & 7;
        const float* rowp = sR + row * 128;
        bf16x8 af[4];
        #pragma unroll
        for (int ks = 0; ks < 4; ++ks) {
            int c0 = ks * 8 + qh * 2;
            float4 fa = *(const float4*)(rowp + ((c0    ) ^ sw) * 4);
            float4 fb = *(const float4*)(rowp + ((c0 + 1) ^ sw) * 4);
            union { unsigned int u[4]; bf16x8 v; } cv;
            cv.u[0] = pack2bf(fa.x, fa.y);
            cv.u[1] = pack2bf(fa.z, fa.w);
            cv.u[2] = pack2bf(fb.x, fb.y);
            cv.u[3] = pack2bf(fb.z, fb.w);
            af[ks] = cv.v;
        }
        #pragma unroll
        for (int ct = 0; ct < 2; ++ct)
            #pragma unroll
            for (int ks = 0; ks < 4; ++ks)
                acc1[rt][ct] = __builtin_amdgcn_mfma_f32_16x16x32_bf16(af[ks], bW[ct][ks], acc1[rt][ct], 0, 0, 0);
    }

    // ---- epilogue 1: h1 = relu(acc + qv[col]) -> sH (bf16, swizzled) ----
    // C/D layout: col = lane&15, row = (lane>>4)*4 + reg
    #pragma unroll
    for (int ct = 0; ct < 2; ++ct) {
        const int col = wcol + ct * 16 + hl;
        const float q = (ct == 0) ? qv0 : qv1;
        #pragma unroll
        for (int rt = 0; rt < 4; ++rt) {
            #pragma unroll
            for (int j = 0; j < 4; ++j) {
                int row = rt * 16 + qh * 4 + j;
                float h = acc1[rt][ct][j] + q;
                h = h > 0.0f ? h : 0.0f;
                int byte = row * 256 + ((col * 2) ^ ((row & 7) << 4));
                *(unsigned short*)((char*)sH + byte) = f2bf(h);
            }
        }
    }
    WG_BARRIER();   // B2: h1 ready (lgkm only -- e/s loads stay in flight)

    // ---- GEMM2: attn[row,col] = sum_k h1[row,k] * W2[col,k] ----
    f32x4 acc2[4][2] = {};
    #pragma unroll
    for (int rt = 0; rt < 4; ++rt) {
        const int row = rt * 16 + hl;
        const int rsw = (row & 7) << 4;
        bf16x8 af[4];
        #pragma unroll
        for (int ks = 0; ks < 4; ++ks) {
            int byte = row * 256 + ((ks * 64 + qh * 16) ^ rsw);
            af[ks] = *(const bf16x8*)((const char*)sH + byte);
        }
        #pragma unroll
        for (int ct = 0; ct < 2; ++ct)
            #pragma unroll
            for (int ks = 0; ks < 4; ++ks)
                acc2[rt][ct] = __builtin_amdgcn_mfma_f32_16x16x32_bf16(af[ks], bW2[ct][ks], acc2[rt][ct], 0, 0, 0);
    }

    // ---- fused epilogue+gather in registers: p[col] = sum_rows (acc2+b2)*(e-s*r) ----
    // r read back from swizzled f32 LDS at (row,col); bias computed in f32.
    float p0 = 0.f, p1 = 0.f;
    #pragma unroll
    for (int ct = 0; ct < 2; ++ct) {
        const int col = wcol + ct * 16 + hl;
        const float bb = (ct == 0) ? b2v0 : b2v1;
        const int cch = col >> 2, cdw = col & 3;
        float pp = 0.f;
        #pragma unroll
        for (int rt = 0; rt < 4; ++rt) {
            #pragma unroll
            for (int j = 0; j < 4; ++j) {
                int row  = rt * 16 + qh * 4 + j;
                float rv = sR[row * 128 + ((cch ^ (row & 7)) << 2) + cdw];
                float e  = fe[ct * 16 + rt * 4 + j];
                float s  = fs[ct * 16 + rt * 4 + j];
                pp += (acc2[rt][ct][j] + bb) * (e - s * rv);
            }
        }
        if (ct == 0) p0 = pp; else p1 = pp;
    }
    // sum the 4 qh-groups that share each col
    p0 += __shfl_xor(p0, 16); p0 += __shfl_xor(p0, 32);
    p1 += __shfl_xor(p1, 16); p1 += __shfl_xor(p1, 32);
    if (qh == 0) {
        sFin[wcol + hl]      = p0;
        sFin[wcol + 16 + hl] = p1;
    }
    WG_BARRIER();   // B3: sFin ready

    // ---- final: normalize + add query_emb ----
    float fv = 0.f;
    if (tid < 128) {
        fv = sFin[tid];
        float rn = fabsf(fv), qn = fabsf(qe);
        #pragma unroll
        for (int off = 1; off < 64; off <<= 1) {
            rn += __shfl_xor(rn, off);
            qn += __shfl_xor(qn, off);
        }
        if (lane == 0) { sRed[wv * 2] = rn; sRed[wv * 2 + 1] = qn; }
    }
    WG_BARRIER();   // B4: sRed ready
    if (tid < 128) {
        float RN = sRed[0] + sRed[2];
        float QN = sRed[1] + sRed[3];
        float scale = 1.0f / (1e-9f + (RN / QN) * 2.5f);
        out[(size_t)b * 128 + tid] = qe + fv * scale;
    }
}

extern "C" void kernel_launch(void* const* d_in, const int* in_sizes, int n_in,
                              void* d_out, int out_size, void* d_ws, size_t ws_size,
                              hipStream_t stream) {
    const float* query_emb  = (const float*)d_in[0];
    const float* refer_embs = (const float*)d_in[1];
    const float* query_r    = (const float*)d_in[2];
    const float* refer_r    = (const float*)d_in[3];
    const float* start_embs = (const float*)d_in[4];
    const float* W1         = (const float*)d_in[5];
    const float* b1         = (const float*)d_in[6];
    const float* W2         = (const float*)d_in[7];
    const float* b2         = (const float*)d_in[8];
    float* out = (float*)d_out;

    char* ws = (char*)d_ws;
    float* qv            = (float*)ws;                              // 4096*128*4 = 2 MB
    unsigned short* w1b  = (unsigned short*)(ws + 2 * 1024 * 1024); // 32 KB
    unsigned short* w2b  = w1b + 16384;                             // 32 KB

    pa_prep<<<128, 256, 0, stream>>>(W1, W2, w1b, w2b);
    pa_qv<<<128, 256, 0, stream>>>(query_r, W1, b1, qv);
    pa_main<<<4096, 256, 0, stream>>>(query_emb, refer_embs, refer_r, start_embs,
                                      qv, w1b, w2b, b2, out);
}